// Round 2
// baseline (731.444 us; speedup 1.0000x reference)
//
#include <hip/hip_runtime.h>
#include <hip/hip_bf16.h>

using bf16 = __hip_bfloat16;

#define F 64
#define HG 128
#define HL 128
#define AVG_LOG_INV 0.45511961331341866f  // 1/log(9)

__device__ __forceinline__ float b2f(bf16 v) { return __bfloat162float(v); }
__device__ __forceinline__ bf16 f2b(float v) { return __float2bfloat16(v); }

__device__ __forceinline__ float wave_sum(float v) {
    #pragma unroll
    for (int m = 32; m > 0; m >>= 1) v += __shfl_xor(v, m);
    return v;
}

__device__ __forceinline__ int lowerb(const int* a, int n, int v) {
    int lo = 0, hi = n;
    while (lo < hi) { int m = (lo + hi) >> 1; if (a[m] < v) lo = m + 1; else hi = m; }
    return lo;
}

// u[f] = sum_k W_edge[k]*Wpre3[k][f];  c[f] = b_pre[f] + sum_k b_edge[k]*Wpre3[k][f]
__global__ void k_uc(const float* W_edge, const float* b_edge, const float* W_pre,
                     const float* b_pre, float* uc) {
    int f = threadIdx.x;  // 64
    float u = 0.f, c = b_pre[f];
    for (int k = 0; k < 64; k++) {
        float w3 = W_pre[(128 + k) * 64 + f];
        u += W_edge[k] * w3;
        c += b_edge[k] * w3;
    }
    uc[f] = u; uc[64 + f] = c;
}

// AB[n][0:64] = x[n]@Wpre1, AB[n][64:128] = x[n]@Wpre2  (bf16 out, internal)
__global__ void k_ab(const float* __restrict__ x, const float* __restrict__ W_pre,
                     bf16* __restrict__ AB, int N) {
    __shared__ float w1[64 * 64], w2[64 * 64];
    for (int i = threadIdx.x; i < 4096; i += blockDim.x) {
        w1[i] = W_pre[i];
        w2[i] = W_pre[4096 + i];
    }
    __syncthreads();
    int lane = threadIdx.x & 63;
    int wid = (blockIdx.x * blockDim.x + threadIdx.x) >> 6;
    int nw = (gridDim.x * blockDim.x) >> 6;
    for (int n = wid; n < N; n += nw) {
        float xv = x[(size_t)n * 64 + lane];
        float a0 = 0.f, a1 = 0.f;
        #pragma unroll
        for (int k = 0; k < 64; k++) {
            float xs = __shfl(xv, k);
            a0 += xs * w1[k * 64 + lane];
            a1 += xs * w2[k * 64 + lane];
        }
        AB[(size_t)n * 128 + lane] = f2b(a0);
        AB[(size_t)n * 128 + 64 + lane] = f2b(a1);
    }
}

__global__ void k_zero(int* __restrict__ p, int n) {
    int i = blockIdx.x * blockDim.x + threadIdx.x;
    if (i < n) p[i] = 0;
}

__global__ void k_hist(const int* __restrict__ ei, int* __restrict__ cnt, int E) {
    int e = blockIdx.x * blockDim.x + threadIdx.x;
    if (e < E) atomicAdd(&cnt[ei[E + e]], 1);
}

__global__ void k_scan1(const int* __restrict__ cnt, int* __restrict__ csum, int N) {
    __shared__ int s[256];
    int i = blockIdx.x * 256 + threadIdx.x;
    s[threadIdx.x] = (i < N) ? cnt[i] : 0;
    __syncthreads();
    for (int st = 128; st > 0; st >>= 1) {
        if (threadIdx.x < st) s[threadIdx.x] += s[threadIdx.x + st];
        __syncthreads();
    }
    if (threadIdx.x == 0) csum[blockIdx.x] = s[0];
}

// exclusive scan of csum[0..NCH), NCH <= 256
__global__ void k_scan2(int* csum, int NCH) {
    __shared__ int s[256];
    int t = threadIdx.x;
    int v = (t < NCH) ? csum[t] : 0;
    s[t] = v;
    __syncthreads();
    for (int st = 1; st < 256; st <<= 1) {
        int a = (t >= st) ? s[t - st] : 0;
        __syncthreads();
        s[t] += a;
        __syncthreads();
    }
    if (t < NCH) csum[t] = s[t] - v;
}

__global__ void k_scan3(const int* __restrict__ cnt, const int* __restrict__ csum,
                        int* __restrict__ offs, int* __restrict__ cursor, int N, int E) {
    __shared__ int s[256];
    int t = threadIdx.x;
    int i = blockIdx.x * 256 + t;
    int v = (i < N) ? cnt[i] : 0;
    s[t] = v;
    __syncthreads();
    for (int st = 1; st < 256; st <<= 1) {
        int a = (t >= st) ? s[t - st] : 0;
        __syncthreads();
        s[t] += a;
        __syncthreads();
    }
    int excl = s[t] - v + csum[blockIdx.x];
    if (i < N) { offs[i] = excl; cursor[i] = excl; }
    if (i == 0) offs[N] = E;
}

__global__ void k_scatter(const int* __restrict__ ei, const float* __restrict__ ea,
                          int* __restrict__ cursor, int* __restrict__ ssrc,
                          float* __restrict__ sea, int E) {
    int e = blockIdx.x * blockDim.x + threadIdx.x;
    if (e >= E) return;
    int d = ei[E + e];
    int p = atomicAdd(&cursor[d], 1);
    ssrc[p] = ei[e];
    sea[p] = ea[e];
}

// one wave per node; lane = feature
__global__ void k_edge(const bf16* __restrict__ AB, const int* __restrict__ offs,
                       const int* __restrict__ ssrc, const float* __restrict__ sea,
                       const float* __restrict__ uc, bf16* __restrict__ agg,
                       float* __restrict__ ampv, int N) {
    int lane = threadIdx.x & 63;
    int n = (blockIdx.x * blockDim.x + threadIdx.x) >> 6;
    if (n >= N) return;
    int lo = offs[n], hi = offs[n + 1];
    float a = b2f(AB[(size_t)n * 128 + lane]);
    float u = uc[lane], c = uc[64 + lane];
    float s = 0.f, sq = 0.f, mn = 3.4e38f, mx = -3.4e38f;
    for (int e = lo; e < hi; ++e) {
        int sn = ssrc[e];
        float eav = sea[e];
        float m = a + b2f(AB[(size_t)sn * 128 + 64 + lane]) + eav * u + c;
        s += m; sq += m * m;
        mn = fminf(mn, m); mx = fmaxf(mx, m);
    }
    int cnt = hi - lo;
    float c1 = (cnt > 0) ? (float)cnt : 1.f;
    float mean = s / c1, m2 = sq / c1;
    float var = m2 - mean * mean;
    if (var < 0.f) var = 0.f;
    float sd = sqrtf(var + 1e-5f);
    if (cnt == 0) { mn = 0.f; mx = 0.f; }
    size_t b = (size_t)n * 256;
    agg[b + lane] = f2b(mean);
    agg[b + 64 + lane] = f2b(mn);
    agg[b + 128 + lane] = f2b(mx);
    agg[b + 192 + lane] = f2b(sd);
    if (lane == 0) ampv[n] = logf(c1 + 1.f) * AVG_LOG_INV;
}

// per-graph mean of 832-dim feature vector [x | agg | agg*amp | agg/amp]
__global__ void k_greduce(const float* __restrict__ x, const bf16* __restrict__ agg,
                          const float* __restrict__ ampv, const int* __restrict__ batch,
                          float* __restrict__ gfeat, int* __restrict__ gcnt, int N) {
    __shared__ int sl[2];
    int g = blockIdx.x, t = threadIdx.x;  // 256 threads
    if (t == 0) sl[0] = lowerb(batch, N, g);
    if (t == 1) sl[1] = lowerb(batch, N, g + 1);
    __syncthreads();
    int lo = sl[0], hi = sl[1];
    float s1 = 0.f, s2 = 0.f, s3 = 0.f, sx = 0.f;
    for (int n = lo; n < hi; n++) {
        float amp = ampv[n];
        float ra = 1.f / amp;
        float av = b2f(agg[(size_t)n * 256 + t]);
        s1 += av; s2 += av * amp; s3 += av * ra;
        if (t < 64) sx += x[(size_t)n * 64 + t];
    }
    int cg = hi - lo;
    float r = 1.f / ((cg > 0) ? (float)cg : 1.f);
    if (t < 64) gfeat[g * 832 + t] = sx * r;
    gfeat[g * 832 + 64 + t] = s1 * r;
    gfeat[g * 832 + 320 + t] = s2 * r;
    gfeat[g * 832 + 576 + t] = s3 * r;
    if (t == 0) gcnt[g] = cg;
}

// Zin[g] = (mean_feat[g] @ W_post + b_post) @ W_lin + b_lin ; zero if empty graph
__global__ void k_post1(const float* __restrict__ gfeat, const int* __restrict__ gcnt,
                        const float* __restrict__ W_post, const float* __restrict__ b_post,
                        const float* __restrict__ W_lin, const float* __restrict__ b_lin,
                        float* __restrict__ Zin) {
    int g = blockIdx.x, j = threadIdx.x;  // 128
    __shared__ float feat[832];
    __shared__ float z1[128];
    for (int i = j; i < 832; i += 128) feat[i] = gfeat[g * 832 + i];
    __syncthreads();
    float acc = b_post[j];
    for (int k = 0; k < 832; k++) acc += feat[k] * W_post[k * 128 + j];
    z1[j] = acc;
    __syncthreads();
    float a2 = b_lin[j];
    for (int k = 0; k < 128; k++) a2 += z1[k] * W_lin[k * 128 + j];
    if (gcnt[g] == 0) a2 = 0.f;
    Zin[g * 128 + j] = a2;
}

// z2 = relu(bn2(relu(bn1(Zin)) @ W2 + b2)) ; block = column j, 64 threads = rows
__global__ void k_mlp1(const float* __restrict__ Zin,
                       const float* g1, const float* be1,
                       const float* __restrict__ W2, const float* b2,
                       const float* g2, const float* be2,
                       float* __restrict__ z2out) {
    __shared__ float Z[64 * 129];
    int t = threadIdx.x, j = blockIdx.x;
    for (int i = t; i < 8192; i += 64) {
        int r = i >> 7, c = i & 127;
        Z[r * 129 + c] = Zin[i];
    }
    __syncthreads();
    #pragma unroll
    for (int cc = 0; cc < 2; cc++) {
        int c = t + cc * 64;
        float mu = 0.f;
        for (int r = 0; r < 64; r++) mu += Z[r * 129 + c];
        mu *= (1.f / 64.f);
        float var = 0.f;
        for (int r = 0; r < 64; r++) { float d = Z[r * 129 + c] - mu; var += d * d; }
        var *= (1.f / 64.f);
        float sc = rsqrtf(var + 1e-5f) * g1[c];
        float sh = be1[c];
        for (int r = 0; r < 64; r++) {
            float v = (Z[r * 129 + c] - mu) * sc + sh;
            Z[r * 129 + c] = v > 0.f ? v : 0.f;
        }
    }
    __syncthreads();
    float acc = b2[j];
    for (int k = 0; k < 128; k++) acc += Z[t * 129 + k] * W2[k * 128 + j];
    float mu = wave_sum(acc) * (1.f / 64.f);
    float d = acc - mu;
    float var = wave_sum(d * d) * (1.f / 64.f);
    float v = d * rsqrtf(var + 1e-5f) * g2[j] + be2[j];
    z2out[t * 128 + j] = v > 0.f ? v : 0.f;
}

// zout = relu(bn(zin @ W + b))
__global__ void k_mlp2(const float* __restrict__ zin,
                       const float* __restrict__ W, const float* b,
                       const float* gg, const float* bb,
                       float* __restrict__ zout) {
    __shared__ float Z[64 * 129];
    int t = threadIdx.x, j = blockIdx.x;
    for (int i = t; i < 8192; i += 64) {
        int r = i >> 7, c = i & 127;
        Z[r * 129 + c] = zin[i];
    }
    __syncthreads();
    float acc = b[j];
    for (int k = 0; k < 128; k++) acc += Z[t * 129 + k] * W[k * 128 + j];
    float mu = wave_sum(acc) * (1.f / 64.f);
    float d = acc - mu;
    float var = wave_sum(d * d) * (1.f / 64.f);
    float v = d * rsqrtf(var + 1e-5f) * gg[j] + bb[j];
    zout[t * 128 + j] = v > 0.f ? v : 0.f;
}

// zout = relu(bn(zin @ W + b) + res)
__global__ void k_mlp3(const float* __restrict__ zin, const float* __restrict__ res,
                       const float* __restrict__ W, const float* b,
                       const float* gg, const float* bb,
                       float* __restrict__ zout) {
    __shared__ float Z[64 * 129];
    int t = threadIdx.x, j = blockIdx.x;
    for (int i = t; i < 8192; i += 64) {
        int r = i >> 7, c = i & 127;
        Z[r * 129 + c] = zin[i];
    }
    __syncthreads();
    float acc = b[j];
    for (int k = 0; k < 128; k++) acc += Z[t * 129 + k] * W[k * 128 + j];
    float mu = wave_sum(acc) * (1.f / 64.f);
    float d = acc - mu;
    float var = wave_sum(d * d) * (1.f / 64.f);
    float v = d * rsqrtf(var + 1e-5f) * gg[j] + bb[j] + res[t * 128 + j];
    zout[t * 128 + j] = v > 0.f ? v : 0.f;
}

__global__ void k_out(const float* __restrict__ z4, const float* __restrict__ W_out,
                      const float* b_out, float* __restrict__ out) {
    int g = threadIdx.x;  // 64
    float acc = b_out[0];
    for (int j = 0; j < 128; j++) acc += z4[g * 128 + j] * W_out[j];
    out[g] = acc;
}

extern "C" void kernel_launch(void* const* d_in, const int* in_sizes, int n_in,
                              void* d_out, int out_size, void* d_ws, size_t ws_size,
                              hipStream_t stream) {
    const float* x      = (const float*)d_in[0];
    const int*   ei     = (const int*)d_in[1];
    const float* ea     = (const float*)d_in[2];
    const int*   batch  = (const int*)d_in[3];
    const float* W_edge = (const float*)d_in[4];
    const float* b_edge = (const float*)d_in[5];
    const float* W_pre  = (const float*)d_in[6];
    const float* b_pre  = (const float*)d_in[7];
    const float* W_post = (const float*)d_in[8];
    const float* b_post = (const float*)d_in[9];
    const float* W_lin  = (const float*)d_in[10];
    const float* b_lin  = (const float*)d_in[11];
    const float* g1     = (const float*)d_in[12];
    const float* be1    = (const float*)d_in[13];
    const float* W2     = (const float*)d_in[14];
    const float* b2     = (const float*)d_in[15];
    const float* g2     = (const float*)d_in[16];
    const float* be2    = (const float*)d_in[17];
    const float* Wr1    = (const float*)d_in[18];
    const float* br1    = (const float*)d_in[19];
    const float* gr1    = (const float*)d_in[20];
    const float* ber1   = (const float*)d_in[21];
    const float* Wr2    = (const float*)d_in[22];
    const float* br2    = (const float*)d_in[23];
    const float* gr2    = (const float*)d_in[24];
    const float* ber2   = (const float*)d_in[25];
    const float* W_out  = (const float*)d_in[26];
    const float* b_out  = (const float*)d_in[27];
    float* out = (float*)d_out;

    const int N = in_sizes[0] / F;      // 50000
    const int E = in_sizes[1] / 2;      // 800000
    const int G = out_size;             // 64

    // workspace carve-up (256B aligned)
    char* p = (char*)d_ws;
    auto alloc = [&](size_t nbytes) { void* r = p; p += (nbytes + 255) & ~(size_t)255; return r; };
    bf16*  AB     = (bf16*)alloc((size_t)N * 128 * sizeof(bf16));
    bf16*  agg    = (bf16*)alloc((size_t)N * 256 * sizeof(bf16));
    float* ampv   = (float*)alloc((size_t)N * sizeof(float));
    int*   cnt    = (int*)alloc((size_t)N * sizeof(int));
    int*   offs   = (int*)alloc((size_t)(N + 1) * sizeof(int));
    int*   cursor = (int*)alloc((size_t)N * sizeof(int));
    int*   csum   = (int*)alloc(512 * sizeof(int));
    int*   ssrc   = (int*)alloc((size_t)E * sizeof(int));
    float* sea    = (float*)alloc((size_t)E * sizeof(float));
    float* uc     = (float*)alloc(128 * sizeof(float));
    float* gfeat  = (float*)alloc((size_t)G * 832 * sizeof(float));
    int*   gcnt   = (int*)alloc((size_t)G * sizeof(int));
    float* Zin    = (float*)alloc(64 * 128 * sizeof(float));
    float* z2b    = (float*)alloc(64 * 128 * sizeof(float));
    float* z3b    = (float*)alloc(64 * 128 * sizeof(float));
    float* z4b    = (float*)alloc(64 * 128 * sizeof(float));

    const int NCH = (N + 255) / 256;    // 196 (must be <= 256)
    const int EB = (E + 255) / 256;

    k_zero<<<NCH, 256, 0, stream>>>(cnt, N);
    k_uc<<<1, 64, 0, stream>>>(W_edge, b_edge, W_pre, b_pre, uc);
    k_ab<<<1024, 256, 0, stream>>>(x, W_pre, AB, N);
    k_hist<<<EB, 256, 0, stream>>>(ei, cnt, E);
    k_scan1<<<NCH, 256, 0, stream>>>(cnt, csum, N);
    k_scan2<<<1, 256, 0, stream>>>(csum, NCH);
    k_scan3<<<NCH, 256, 0, stream>>>(cnt, csum, offs, cursor, N, E);
    k_scatter<<<EB, 256, 0, stream>>>(ei, ea, cursor, ssrc, sea, E);
    k_edge<<<(N * 64 + 255) / 256, 256, 0, stream>>>(AB, offs, ssrc, sea, uc, agg, ampv, N);
    k_greduce<<<G, 256, 0, stream>>>(x, agg, ampv, batch, gfeat, gcnt, N);
    k_post1<<<G, 128, 0, stream>>>(gfeat, gcnt, W_post, b_post, W_lin, b_lin, Zin);
    k_mlp1<<<128, 64, 0, stream>>>(Zin, g1, be1, W2, b2, g2, be2, z2b);
    k_mlp2<<<128, 64, 0, stream>>>(z2b, Wr1, br1, gr1, ber1, z3b);
    k_mlp3<<<128, 64, 0, stream>>>(z3b, z2b, Wr2, br2, gr2, ber2, z4b);
    k_out<<<1, 64, 0, stream>>>(z4b, W_out, b_out, out);
}

// Round 3
// 504.590 us; speedup vs baseline: 1.4496x; 1.4496x over previous
//
#include <hip/hip_runtime.h>
#include <hip/hip_bf16.h>

using bf16 = __hip_bfloat16;

#define F 64
#define HG 128
#define HL 128
#define AVG_LOG_INV 0.45511961331341866f  // 1/log(9)

__device__ __forceinline__ float b2f(bf16 v) { return __bfloat162float(v); }
__device__ __forceinline__ bf16 f2b(float v) { return __float2bfloat16(v); }

__device__ __forceinline__ float wave_sum(float v) {
    #pragma unroll
    for (int m = 32; m > 0; m >>= 1) v += __shfl_xor(v, m);
    return v;
}

// u[f] = sum_k W_edge[k]*Wpre3[k][f];  c[f] = b_pre[f] + sum_k b_edge[k]*Wpre3[k][f]
__global__ void k_uc(const float* W_edge, const float* b_edge, const float* W_pre,
                     const float* b_pre, float* uc) {
    int f = threadIdx.x;  // 64
    float u = 0.f, c = b_pre[f];
    for (int k = 0; k < 64; k++) {
        float w3 = W_pre[(128 + k) * 64 + f];
        u += W_edge[k] * w3;
        c += b_edge[k] * w3;
    }
    uc[f] = u; uc[64 + f] = c;
}

// AB[n][0:64] = x[n]@Wpre1, AB[n][64:128] = x[n]@Wpre2  (bf16 out, internal)
__global__ void k_ab(const float* __restrict__ x, const float* __restrict__ W_pre,
                     bf16* __restrict__ AB, int N) {
    __shared__ float w1[64 * 64], w2[64 * 64];
    for (int i = threadIdx.x; i < 4096; i += blockDim.x) {
        w1[i] = W_pre[i];
        w2[i] = W_pre[4096 + i];
    }
    __syncthreads();
    int lane = threadIdx.x & 63;
    int wid = (blockIdx.x * blockDim.x + threadIdx.x) >> 6;
    int nw = (gridDim.x * blockDim.x) >> 6;
    for (int n = wid; n < N; n += nw) {
        float xv = x[(size_t)n * 64 + lane];
        float a0 = 0.f, a1 = 0.f;
        #pragma unroll
        for (int k = 0; k < 64; k++) {
            float xs = __shfl(xv, k);
            a0 += xs * w1[k * 64 + lane];
            a1 += xs * w2[k * 64 + lane];
        }
        AB[(size_t)n * 128 + lane] = f2b(a0);
        AB[(size_t)n * 128 + 64 + lane] = f2b(a1);
    }
}

__global__ void k_zero(int* __restrict__ p, int n) {
    int i = blockIdx.x * blockDim.x + threadIdx.x;
    if (i < n) p[i] = 0;
}

__global__ void k_hist(const int* __restrict__ ei, int* __restrict__ cnt, int E) {
    int e = blockIdx.x * blockDim.x + threadIdx.x;
    if (e < E) atomicAdd(&cnt[ei[E + e]], 1);
}

__global__ void k_scan1(const int* __restrict__ cnt, int* __restrict__ csum, int N) {
    __shared__ int s[256];
    int i = blockIdx.x * 256 + threadIdx.x;
    s[threadIdx.x] = (i < N) ? cnt[i] : 0;
    __syncthreads();
    for (int st = 128; st > 0; st >>= 1) {
        if (threadIdx.x < st) s[threadIdx.x] += s[threadIdx.x + st];
        __syncthreads();
    }
    if (threadIdx.x == 0) csum[blockIdx.x] = s[0];
}

// exclusive scan of csum[0..NCH), NCH <= 256
__global__ void k_scan2(int* csum, int NCH) {
    __shared__ int s[256];
    int t = threadIdx.x;
    int v = (t < NCH) ? csum[t] : 0;
    s[t] = v;
    __syncthreads();
    for (int st = 1; st < 256; st <<= 1) {
        int a = (t >= st) ? s[t - st] : 0;
        __syncthreads();
        s[t] += a;
        __syncthreads();
    }
    if (t < NCH) csum[t] = s[t] - v;
}

__global__ void k_scan3(const int* __restrict__ cnt, const int* __restrict__ csum,
                        int* __restrict__ offs, int* __restrict__ cursor, int N, int E) {
    __shared__ int s[256];
    int t = threadIdx.x;
    int i = blockIdx.x * 256 + t;
    int v = (i < N) ? cnt[i] : 0;
    s[t] = v;
    __syncthreads();
    for (int st = 1; st < 256; st <<= 1) {
        int a = (t >= st) ? s[t - st] : 0;
        __syncthreads();
        s[t] += a;
        __syncthreads();
    }
    int excl = s[t] - v + csum[blockIdx.x];
    if (i < N) { offs[i] = excl; cursor[i] = excl; }
    if (i == 0) offs[N] = E;
}

__global__ void k_scatter(const int* __restrict__ ei, const float* __restrict__ ea,
                          int* __restrict__ cursor, int* __restrict__ ssrc,
                          float* __restrict__ sea, int E) {
    int e = blockIdx.x * blockDim.x + threadIdx.x;
    if (e >= E) return;
    int d = ei[E + e];
    int p = atomicAdd(&cursor[d], 1);
    ssrc[p] = ei[e];
    sea[p] = ea[e];
}

// one wave per node; lane = feature
__global__ void k_edge(const bf16* __restrict__ AB, const int* __restrict__ offs,
                       const int* __restrict__ ssrc, const float* __restrict__ sea,
                       const float* __restrict__ uc, bf16* __restrict__ agg,
                       float* __restrict__ ampv, int N) {
    int lane = threadIdx.x & 63;
    int n = (blockIdx.x * blockDim.x + threadIdx.x) >> 6;
    if (n >= N) return;
    int lo = offs[n], hi = offs[n + 1];
    float a = b2f(AB[(size_t)n * 128 + lane]);
    float u = uc[lane], c = uc[64 + lane];
    float s = 0.f, sq = 0.f, mn = 3.4e38f, mx = -3.4e38f;
    for (int e = lo; e < hi; ++e) {
        int sn = ssrc[e];
        float eav = sea[e];
        float m = a + b2f(AB[(size_t)sn * 128 + 64 + lane]) + eav * u + c;
        s += m; sq += m * m;
        mn = fminf(mn, m); mx = fmaxf(mx, m);
    }
    int cnt = hi - lo;
    float c1 = (cnt > 0) ? (float)cnt : 1.f;
    float mean = s / c1, m2 = sq / c1;
    float var = m2 - mean * mean;
    if (var < 0.f) var = 0.f;
    float sd = sqrtf(var + 1e-5f);
    if (cnt == 0) { mn = 0.f; mx = 0.f; }
    size_t b = (size_t)n * 256;
    agg[b + lane] = f2b(mean);
    agg[b + 64 + lane] = f2b(mn);
    agg[b + 128 + lane] = f2b(mx);
    agg[b + 192 + lane] = f2b(sd);
    if (lane == 0) ampv[n] = logf(c1 + 1.f) * AVG_LOG_INV;
}

// chunked per-graph SUM of 832-dim feature vector [x | agg | agg*amp | agg/amp]
// batch is sorted: accumulate in registers, flush via atomicAdd at graph boundaries
__global__ void k_greduce2(const float* __restrict__ x, const bf16* __restrict__ agg,
                           const float* __restrict__ ampv, const int* __restrict__ batch,
                           float* __restrict__ gfeat, int* __restrict__ gcnt,
                           int N, int chunk) {
    int t = threadIdx.x;  // 256
    int lo = blockIdx.x * chunk;
    int hi = lo + chunk; if (hi > N) hi = N;
    if (lo >= hi) return;
    int curg = batch[lo];
    float s1 = 0.f, s2 = 0.f, s3 = 0.f, sx = 0.f;
    int cnt = 0;
    for (int n = lo; n < hi; n++) {
        int g = batch[n];
        if (g != curg) {
            float* gf = gfeat + (size_t)curg * 832;
            atomicAdd(&gf[64 + t], s1);
            atomicAdd(&gf[320 + t], s2);
            atomicAdd(&gf[576 + t], s3);
            if (t < 64) atomicAdd(&gf[t], sx);
            if (t == 0) atomicAdd(&gcnt[curg], cnt);
            s1 = s2 = s3 = sx = 0.f; cnt = 0; curg = g;
        }
        float amp = ampv[n];
        float av = b2f(agg[(size_t)n * 256 + t]);
        s1 += av; s2 += av * amp; s3 += av / amp;
        if (t < 64) sx += x[(size_t)n * 64 + t];
        cnt++;
    }
    float* gf = gfeat + (size_t)curg * 832;
    atomicAdd(&gf[64 + t], s1);
    atomicAdd(&gf[320 + t], s2);
    atomicAdd(&gf[576 + t], s3);
    if (t < 64) atomicAdd(&gf[t], sx);
    if (t == 0) atomicAdd(&gcnt[curg], cnt);
}

// Zin[g] = ((gfeat[g]/cnt) @ W_post + b_post) @ W_lin + b_lin ; zero if empty graph
__global__ void k_post1(const float* __restrict__ gfeat, const int* __restrict__ gcnt,
                        const float* __restrict__ W_post, const float* __restrict__ b_post,
                        const float* __restrict__ W_lin, const float* __restrict__ b_lin,
                        float* __restrict__ Zin) {
    int g = blockIdx.x, j = threadIdx.x;  // 128
    __shared__ float feat[832];
    __shared__ float z1[128];
    int cg = gcnt[g];
    float r = 1.f / ((cg > 0) ? (float)cg : 1.f);
    for (int i = j; i < 832; i += 128) feat[i] = gfeat[(size_t)g * 832 + i] * r;
    __syncthreads();
    float acc = b_post[j];
    for (int k = 0; k < 832; k++) acc += feat[k] * W_post[k * 128 + j];
    z1[j] = acc;
    __syncthreads();
    float a2 = b_lin[j];
    for (int k = 0; k < 128; k++) a2 += z1[k] * W_lin[k * 128 + j];
    if (cg == 0) a2 = 0.f;
    Zin[g * 128 + j] = a2;
}

// z2 = relu(bn2(relu(bn1(Zin)) @ W2 + b2)) ; block = column j, 64 threads = rows
__global__ void k_mlp1(const float* __restrict__ Zin,
                       const float* g1, const float* be1,
                       const float* __restrict__ W2, const float* b2,
                       const float* g2, const float* be2,
                       float* __restrict__ z2out) {
    __shared__ float Z[64 * 129];
    int t = threadIdx.x, j = blockIdx.x;
    for (int i = t; i < 8192; i += 64) {
        int r = i >> 7, c = i & 127;
        Z[r * 129 + c] = Zin[i];
    }
    __syncthreads();
    #pragma unroll
    for (int cc = 0; cc < 2; cc++) {
        int c = t + cc * 64;
        float mu = 0.f;
        for (int r = 0; r < 64; r++) mu += Z[r * 129 + c];
        mu *= (1.f / 64.f);
        float var = 0.f;
        for (int r = 0; r < 64; r++) { float d = Z[r * 129 + c] - mu; var += d * d; }
        var *= (1.f / 64.f);
        float sc = rsqrtf(var + 1e-5f) * g1[c];
        float sh = be1[c];
        for (int r = 0; r < 64; r++) {
            float v = (Z[r * 129 + c] - mu) * sc + sh;
            Z[r * 129 + c] = v > 0.f ? v : 0.f;
        }
    }
    __syncthreads();
    float acc = b2[j];
    for (int k = 0; k < 128; k++) acc += Z[t * 129 + k] * W2[k * 128 + j];
    float mu = wave_sum(acc) * (1.f / 64.f);
    float d = acc - mu;
    float var = wave_sum(d * d) * (1.f / 64.f);
    float v = d * rsqrtf(var + 1e-5f) * g2[j] + be2[j];
    z2out[t * 128 + j] = v > 0.f ? v : 0.f;
}

// zout = relu(bn(zin @ W + b))
__global__ void k_mlp2(const float* __restrict__ zin,
                       const float* __restrict__ W, const float* b,
                       const float* gg, const float* bb,
                       float* __restrict__ zout) {
    __shared__ float Z[64 * 129];
    int t = threadIdx.x, j = blockIdx.x;
    for (int i = t; i < 8192; i += 64) {
        int r = i >> 7, c = i & 127;
        Z[r * 129 + c] = zin[i];
    }
    __syncthreads();
    float acc = b[j];
    for (int k = 0; k < 128; k++) acc += Z[t * 129 + k] * W[k * 128 + j];
    float mu = wave_sum(acc) * (1.f / 64.f);
    float d = acc - mu;
    float var = wave_sum(d * d) * (1.f / 64.f);
    float v = d * rsqrtf(var + 1e-5f) * gg[j] + bb[j];
    zout[t * 128 + j] = v > 0.f ? v : 0.f;
}

// zout = relu(bn(zin @ W + b) + res)
__global__ void k_mlp3(const float* __restrict__ zin, const float* __restrict__ res,
                       const float* __restrict__ W, const float* b,
                       const float* gg, const float* bb,
                       float* __restrict__ zout) {
    __shared__ float Z[64 * 129];
    int t = threadIdx.x, j = blockIdx.x;
    for (int i = t; i < 8192; i += 64) {
        int r = i >> 7, c = i & 127;
        Z[r * 129 + c] = zin[i];
    }
    __syncthreads();
    float acc = b[j];
    for (int k = 0; k < 128; k++) acc += Z[t * 129 + k] * W[k * 128 + j];
    float mu = wave_sum(acc) * (1.f / 64.f);
    float d = acc - mu;
    float var = wave_sum(d * d) * (1.f / 64.f);
    float v = d * rsqrtf(var + 1e-5f) * gg[j] + bb[j] + res[t * 128 + j];
    zout[t * 128 + j] = v > 0.f ? v : 0.f;
}

__global__ void k_out(const float* __restrict__ z4, const float* __restrict__ W_out,
                      const float* b_out, float* __restrict__ out) {
    int g = threadIdx.x;  // 64
    float acc = b_out[0];
    for (int j = 0; j < 128; j++) acc += z4[g * 128 + j] * W_out[j];
    out[g] = acc;
}

extern "C" void kernel_launch(void* const* d_in, const int* in_sizes, int n_in,
                              void* d_out, int out_size, void* d_ws, size_t ws_size,
                              hipStream_t stream) {
    const float* x      = (const float*)d_in[0];
    const int*   ei     = (const int*)d_in[1];
    const float* ea     = (const float*)d_in[2];
    const int*   batch  = (const int*)d_in[3];
    const float* W_edge = (const float*)d_in[4];
    const float* b_edge = (const float*)d_in[5];
    const float* W_pre  = (const float*)d_in[6];
    const float* b_pre  = (const float*)d_in[7];
    const float* W_post = (const float*)d_in[8];
    const float* b_post = (const float*)d_in[9];
    const float* W_lin  = (const float*)d_in[10];
    const float* b_lin  = (const float*)d_in[11];
    const float* g1     = (const float*)d_in[12];
    const float* be1    = (const float*)d_in[13];
    const float* W2     = (const float*)d_in[14];
    const float* b2     = (const float*)d_in[15];
    const float* g2     = (const float*)d_in[16];
    const float* be2    = (const float*)d_in[17];
    const float* Wr1    = (const float*)d_in[18];
    const float* br1    = (const float*)d_in[19];
    const float* gr1    = (const float*)d_in[20];
    const float* ber1   = (const float*)d_in[21];
    const float* Wr2    = (const float*)d_in[22];
    const float* br2    = (const float*)d_in[23];
    const float* gr2    = (const float*)d_in[24];
    const float* ber2   = (const float*)d_in[25];
    const float* W_out  = (const float*)d_in[26];
    const float* b_out  = (const float*)d_in[27];
    float* out = (float*)d_out;

    const int N = in_sizes[0] / F;      // 50000
    const int E = in_sizes[1] / 2;      // 800000
    const int G = out_size;             // 64

    // workspace carve-up (256B aligned)
    char* p = (char*)d_ws;
    auto alloc = [&](size_t nbytes) { void* r = p; p += (nbytes + 255) & ~(size_t)255; return r; };
    bf16*  AB     = (bf16*)alloc((size_t)N * 128 * sizeof(bf16));
    bf16*  agg    = (bf16*)alloc((size_t)N * 256 * sizeof(bf16));
    float* ampv   = (float*)alloc((size_t)N * sizeof(float));
    int*   cnt    = (int*)alloc((size_t)N * sizeof(int));
    int*   offs   = (int*)alloc((size_t)(N + 1) * sizeof(int));
    int*   cursor = (int*)alloc((size_t)N * sizeof(int));
    int*   csum   = (int*)alloc(512 * sizeof(int));
    int*   ssrc   = (int*)alloc((size_t)E * sizeof(int));
    float* sea    = (float*)alloc((size_t)E * sizeof(float));
    float* uc     = (float*)alloc(128 * sizeof(float));
    float* gfeat  = (float*)alloc((size_t)G * 832 * sizeof(float));
    int*   gcnt   = (int*)alloc((size_t)G * sizeof(int));
    float* Zin    = (float*)alloc(64 * 128 * sizeof(float));
    float* z2b    = (float*)alloc(64 * 128 * sizeof(float));
    float* z3b    = (float*)alloc(64 * 128 * sizeof(float));
    float* z4b    = (float*)alloc(64 * 128 * sizeof(float));

    const int NCH = (N + 255) / 256;    // 196 (must be <= 256)
    const int EB = (E + 255) / 256;
    const int GRB = 512;                       // blocks for k_greduce2
    const int GRCH = (N + GRB - 1) / GRB;      // nodes per block

    k_zero<<<NCH, 256, 0, stream>>>(cnt, N);
    k_zero<<<(G * 832 + 255) / 256, 256, 0, stream>>>((int*)gfeat, G * 832);
    k_zero<<<1, 64, 0, stream>>>(gcnt, G);
    k_uc<<<1, 64, 0, stream>>>(W_edge, b_edge, W_pre, b_pre, uc);
    k_ab<<<1024, 256, 0, stream>>>(x, W_pre, AB, N);
    k_hist<<<EB, 256, 0, stream>>>(ei, cnt, E);
    k_scan1<<<NCH, 256, 0, stream>>>(cnt, csum, N);
    k_scan2<<<1, 256, 0, stream>>>(csum, NCH);
    k_scan3<<<NCH, 256, 0, stream>>>(cnt, csum, offs, cursor, N, E);
    k_scatter<<<EB, 256, 0, stream>>>(ei, ea, cursor, ssrc, sea, E);
    k_edge<<<(N * 64 + 255) / 256, 256, 0, stream>>>(AB, offs, ssrc, sea, uc, agg, ampv, N);
    k_greduce2<<<GRB, 256, 0, stream>>>(x, agg, ampv, batch, gfeat, gcnt, N, GRCH);
    k_post1<<<G, 128, 0, stream>>>(gfeat, gcnt, W_post, b_post, W_lin, b_lin, Zin);
    k_mlp1<<<128, 64, 0, stream>>>(Zin, g1, be1, W2, b2, g2, be2, z2b);
    k_mlp2<<<128, 64, 0, stream>>>(z2b, Wr1, br1, gr1, ber1, z3b);
    k_mlp3<<<128, 64, 0, stream>>>(z3b, z2b, Wr2, br2, gr2, ber2, z4b);
    k_out<<<1, 64, 0, stream>>>(z4b, W_out, b_out, out);
}